// Round 7
// baseline (255.407 us; speedup 1.0000x reference)
//
#include <hip/hip_runtime.h>

#define NH 8
#define HD 32
#define NL 4
#define NP 4
#define DM 256
#define LEN_IN_C 13294
#define LQ_C 13294
#define B_C 2
#define M_TOTAL (B_C * LQ_C)           // 26588
#define MT_TILES 1662                  // ceil(26588/16)
#define RT32_TILES 831                 // ceil(26588/32)
#define GQ 32                          // queries per sampler block
#define QBLKS 831                      // ceil(26588/32)
#define FRONT_BLOCKS 512               // persistent: 256 per flavor
#define FRONT_STRIDE 256               // tiles stride per flavor
#define BACK_BLOCKS 512

typedef __attribute__((ext_vector_type(8))) short short8;
typedef __attribute__((ext_vector_type(4))) float floatx4;

__device__ __forceinline__ unsigned short f2bf(float x) {
    union { float f; unsigned int u; } a; a.f = x;
    unsigned int r = (a.u + 0x7FFFu + ((a.u >> 16) & 1u)) >> 16;
    return (unsigned short)r;
}
__device__ __forceinline__ unsigned short f2h(float x) {
    unsigned int r;
    asm("v_cvt_f16_f32 %0, %1" : "=v"(r) : "v"(x));
    return (unsigned short)r;
}
__device__ __forceinline__ unsigned int cvtpk_bf16(float lo, float hi) {
    unsigned int r;
    asm("v_cvt_pk_bf16_f32 %0, %1, %2" : "=v"(r) : "v"(lo), "v"(hi));
    return r;
}

// acc += f16(lo/hi half of v) * w   — one VALU op, f32 accumulate.
#define FMAMIX_LO(acc, v, w) \
    asm("v_fma_mix_f32 %0, %1, %2, %0 op_sel_hi:[1,0,0]" : "+v"(acc) : "v"(v), "v"(w))
#define FMAMIX_HI(acc, v, w) \
    asm("v_fma_mix_f32 %0, %1, %2, %0 op_sel:[1,0,0] op_sel_hi:[1,0,0]" : "+v"(acc) : "v"(v), "v"(w))

// ---------------------------------------------------------------------------
// Weight conversions + bias fuse + pad/tail zeroing in ONE kernel.
// ---------------------------------------------------------------------------
__device__ __forceinline__ void conv_b_body(const float* __restrict__ W,
                                            unsigned short* __restrict__ Bsw,
                                            int Nsrc, int NTsrc, int NTtotal, int ntOff,
                                            int vblk) {
    const int u = vblk * 256 + threadIdx.x;
    const int lane = u & 63;
    const int unit = u >> 6;
    const int ntl = unit % NTsrc;
    const int kc = unit / NTsrc;
    const int n = ntl * 16 + (lane & 15);
    const int k0 = kc * 32 + (lane >> 4) * 8;
    short8 v;
#pragma unroll
    for (int j = 0; j < 8; ++j)
        v[j] = (short)f2bf(W[(size_t)(k0 + j) * Nsrc + n]);
    ((short8*)Bsw)[(size_t)(kc * NTtotal + ntOff + ntl) * 64 + lane] = v;
}

__global__ __launch_bounds__(256) void conv_weights_kernel(const float* __restrict__ Wv,
                                                           const float* __restrict__ Woff,
                                                           const float* __restrict__ Wattn,
                                                           const float* __restrict__ Wout,
                                                           const float* __restrict__ boff,
                                                           const float* __restrict__ battn,
                                                           unsigned short* __restrict__ BswV,
                                                           unsigned short* __restrict__ BswOA,
                                                           unsigned short* __restrict__ BswO,
                                                           float* __restrict__ fbias,
                                                           unsigned short* __restrict__ value,
                                                           unsigned short* __restrict__ AccSw) {
    const int blk = blockIdx.x;
    if (blk < 32)        conv_b_body(Wv,    BswV,  256, 16, 16, 0,  blk);
    else if (blk < 64)   conv_b_body(Woff,  BswOA, 256, 16, 24, 0,  blk - 32);
    else if (blk < 80)   conv_b_body(Wattn, BswOA, 128,  8, 24, 16, blk - 64);
    else if (blk < 112)  conv_b_body(Wout,  BswO,  256, 16, 16, 0,  blk - 80);
    else if (blk < 114) {
        const int t = (blk - 112) * 256 + threadIdx.x;
        if (t < 384) fbias[t] = (t < 256) ? boff[t] : battn[t - 256];
        else if (t < 416) {
            const int j = t - 384;
            value[-32 + j] = 0;                            // front pad (64 B)
            value[(size_t)M_TOTAL * 256 + j] = 0;          // back pad (64 B)
        }
    } else {
        // zero the tail rows 26588..26591 of AccSw (rt=1661, m=12..15)
        const int idx = threadIdx.x;
        if (idx < 128) {
            const int kc = idx >> 4;
            const int sub = idx & 15;
            const int lane = (12 + (sub & 3)) + 16 * (sub >> 2);
            const size_t unit = (size_t)(1661 * 8 + kc) * 64 + lane;
            short8 z = (short8){0, 0, 0, 0, 0, 0, 0, 0};
            ((short8*)AccSw)[unit] = z;
        }
    }
}

// ---------------------------------------------------------------------------
// Front GEMM: PERSISTENT blocks + cross-tile pipeline (T14 async-STAGE).
//   Per tile: issue next tile's 8 float4 loads (regs) -> compute current
//   tile from LDS buf[cur] -> cvt+ds_write regs into buf[nxt] -> barrier.
//   HBM staging latency hides under the current tile's MFMA+B-loads.
// ---------------------------------------------------------------------------
__device__ __forceinline__ void stage_load(float4 (&stg)[8], const float* __restrict__ A,
                                           int trow, int M, int tid) {
#pragma unroll
    for (int i = 0; i < 8; ++i) {
        const int li = i * 1024 + tid * 4;          // float index within tile
        const int lrow = li >> 8;
        const int lcol = li & 255;
        const int srow = min(trow + lrow, M - 1);
        stg[i] = *(const float4*)(A + (size_t)srow * 256 + lcol);
    }
}

__device__ __forceinline__ void stage_write(unsigned short* sbuf, const float4 (&stg)[8], int tid) {
#pragma unroll
    for (int i = 0; i < 8; ++i) {
        const int li = i * 1024 + tid * 4;
        const int lrow = li >> 8;
        uint2 pk;
        pk.x = cvtpk_bf16(stg[i].x, stg[i].y);
        pk.y = cvtpk_bf16(stg[i].z, stg[i].w);
        *(uint2*)((char*)sbuf + ((li * 2) ^ ((lrow & 7) << 4))) = pk;
    }
}

template <int NT, int OUTMODE>
__device__ __forceinline__ void tile_compute(const unsigned short* sbuf,
                                             const unsigned short* __restrict__ Bsw,
                                             const float* __restrict__ bias,
                                             void* __restrict__ Cout, int M, int rt32,
                                             int lane, int wave) {
    constexpr int NTW = NT / 4;
    const int m = lane & 15;
    const int q = lane >> 4;
    const short8* Bu = (const short8*)Bsw;
    const int swz = (m & 7) << 4;
    const int trow = rt32 * 32;

    floatx4 acc[2][NTW];
#pragma unroll
    for (int r = 0; r < 2; ++r)
#pragma unroll
        for (int t = 0; t < NTW; ++t) acc[r][t] = (floatx4){0.f, 0.f, 0.f, 0.f};

    short8 br[2][NTW];
    short8 ar[2][2];
#pragma unroll
    for (int t = 0; t < NTW; ++t)
        br[0][t] = Bu[(size_t)(0 * NT + wave * NTW + t) * 64 + lane];
    ar[0][0] = *(const short8*)((const char*)sbuf + ((m * 512 + 0 * 64 + q * 16) ^ swz));
    ar[0][1] = *(const short8*)((const char*)sbuf + (((m + 16) * 512 + 0 * 64 + q * 16) ^ swz));

#pragma unroll
    for (int kc = 0; kc < 8; ++kc) {
        const int cur = kc & 1;
        const int nxt = cur ^ 1;
        if (kc < 7) {
#pragma unroll
            for (int t = 0; t < NTW; ++t)
                br[nxt][t] = Bu[(size_t)((kc + 1) * NT + wave * NTW + t) * 64 + lane];
            ar[nxt][0] = *(const short8*)((const char*)sbuf + ((m * 512 + (kc + 1) * 64 + q * 16) ^ swz));
            ar[nxt][1] = *(const short8*)((const char*)sbuf + (((m + 16) * 512 + (kc + 1) * 64 + q * 16) ^ swz));
        }
#pragma unroll
        for (int t = 0; t < NTW; ++t) {
            acc[0][t] = __builtin_amdgcn_mfma_f32_16x16x32_bf16(ar[cur][0], br[cur][t], acc[0][t], 0, 0, 0);
            acc[1][t] = __builtin_amdgcn_mfma_f32_16x16x32_bf16(ar[cur][1], br[cur][t], acc[1][t], 0, 0, 0);
        }
    }

    const int N = NT * 16;
    const int colq = lane & 15;
    const int rowq = (lane >> 4) * 4;
#pragma unroll
    for (int t = 0; t < NTW; ++t) {
        const int col = (wave * NTW + t) * 16 + colq;
        const float bc = bias[col];
#pragma unroll
        for (int r = 0; r < 2; ++r) {
#pragma unroll
            for (int reg = 0; reg < 4; ++reg) {
                const int row = trow + r * 16 + rowq + reg;
                if (row < M) {
                    const float v = acc[r][t][reg] + bc;
                    if (OUTMODE == 1) {
                        const int bb = row >= LEN_IN_C;
                        const int pos = row - (bb ? LEN_IN_C : 0);
                        const int hh = col >> 5;
                        const int dd = col & 31;
                        ((unsigned short*)Cout)[((size_t)((bb << 3) + hh) * LEN_IN_C + pos) * 32 + dd] = f2h(v);
                    } else {
                        ((float*)Cout)[(size_t)row * N + col] = v;
                    }
                }
            }
        }
    }
}

__global__ __launch_bounds__(256, 2) void front_gemm_kernel(const float* __restrict__ inflat,
                                                            const float* __restrict__ query,
                                                            const unsigned short* __restrict__ BswV,
                                                            const unsigned short* __restrict__ BswOA,
                                                            const float* __restrict__ bv,
                                                            const float* __restrict__ fbias,
                                                            unsigned short* __restrict__ value,
                                                            float* __restrict__ fused, int M) {
    __shared__ unsigned short sA[2][32 * 256];    // 2 x 16 KB
    const int tid = threadIdx.x;
    const int lane = tid & 63;
    const int wave = tid >> 6;
    const int flavor = blockIdx.x & 1;            // 0: value GEMM, 1: off/attn GEMM
    const int rt0 = blockIdx.x >> 1;              // 0..255
    const float* A = flavor ? query : inflat;

    float4 stg[8];
    stage_load(stg, A, rt0 * 32, M, tid);
    stage_write(sA[0], stg, tid);

    int cur = 0;
    for (int rt = rt0; rt < RT32_TILES; rt += FRONT_STRIDE) {
        __syncthreads();                          // buf[cur] ready; prev reads done
        const int rtn = rt + FRONT_STRIDE;
        if (rtn < RT32_TILES) stage_load(stg, A, rtn * 32, M, tid);   // async issue
        if (flavor == 0)
            tile_compute<16, 1>(sA[cur], BswV, bv, (void*)value, M, rt, lane, wave);
        else
            tile_compute<24, 0>(sA[cur], BswOA, fbias, (void*)fused, M, rt, lane, wave);
        if (rtn < RT32_TILES) stage_write(sA[cur ^ 1], stg, tid);
        cur ^= 1;
    }
}

// ---------------------------------------------------------------------------
// Back GEMM: PERSISTENT blocks, B resident in REGISTERS (loaded once,
// 32 short8/wave), A-fragments for tile t+1 prefetched under tile t's MFMA
// (static two-bank unroll). 16-row tiles, 1662 jobs over 512 blocks.
// ---------------------------------------------------------------------------
__device__ __forceinline__ void back_loadA(short8 (&ar)[8], const short8* __restrict__ Au,
                                           int rt, int lane) {
#pragma unroll
    for (int kc = 0; kc < 8; ++kc)
        ar[kc] = Au[(size_t)(rt * 8 + kc) * 64 + lane];
}

__device__ __forceinline__ void back_compute(const short8 (&ar)[8], const short8 (&br)[8][4],
                                             const float* __restrict__ bias,
                                             float* __restrict__ Cout, int M, int rt,
                                             int lane, int wave) {
    floatx4 acc[4];
#pragma unroll
    for (int t = 0; t < 4; ++t) acc[t] = (floatx4){0.f, 0.f, 0.f, 0.f};
#pragma unroll
    for (int kc = 0; kc < 8; ++kc)
#pragma unroll
        for (int t = 0; t < 4; ++t)
            acc[t] = __builtin_amdgcn_mfma_f32_16x16x32_bf16(ar[kc], br[kc][t], acc[t], 0, 0, 0);

    const int colq = lane & 15;
    const int rowq = (lane >> 4) * 4;
#pragma unroll
    for (int t = 0; t < 4; ++t) {
        const int col = (wave * 4 + t) * 16 + colq;
        const float bc = bias[col];
#pragma unroll
        for (int reg = 0; reg < 4; ++reg) {
            const int row = rt * 16 + rowq + reg;
            if (row < M)
                Cout[(size_t)row * 256 + col] = acc[t][reg] + bc;
        }
    }
}

__global__ __launch_bounds__(256, 2) void back_gemm_kernel(const unsigned short* __restrict__ Asw,
                                                           const unsigned short* __restrict__ Bsw,
                                                           const float* __restrict__ bias,
                                                           float* __restrict__ Cout, int M) {
    const int tid = threadIdx.x;
    const int lane = tid & 63;
    const int wave = tid >> 6;
    const short8* Au = (const short8*)Asw;
    const short8* Bu = (const short8*)Bsw;

    // B resident: 8 kc x 4 nt fragments (this wave's output columns)
    short8 br[8][4];
#pragma unroll
    for (int kc = 0; kc < 8; ++kc)
#pragma unroll
        for (int t = 0; t < 4; ++t)
            br[kc][t] = Bu[(size_t)(kc * 16 + wave * 4 + t) * 64 + lane];

    short8 arA[8], arB[8];
    int rt = blockIdx.x;
    if (rt >= MT_TILES) return;
    back_loadA(arA, Au, rt, lane);
    while (true) {
        int rtn = rt + BACK_BLOCKS;
        if (rtn < MT_TILES) back_loadA(arB, Au, rtn, lane);   // prefetch
        back_compute(arA, br, bias, Cout, M, rt, lane, wave);
        rt = rtn;
        if (rt >= MT_TILES) break;
        rtn = rt + BACK_BLOCKS;
        if (rtn < MT_TILES) back_loadA(arA, Au, rtn, lane);   // prefetch
        back_compute(arB, br, bias, Cout, M, rt, lane, wave);
        rt = rtn;
        if (rt >= MT_TILES) break;
    }
}

// ---------------------------------------------------------------------------
// Sampler v8 (unchanged): head-per-XCD + FP16 value + v_fma_mix_f32,
// 4-point chunked double-buffered gather pipeline.
// ---------------------------------------------------------------------------
__global__ __launch_bounds__(256, 4) void msda_sample_kernel(const float* __restrict__ refp,
                                                             const unsigned short* __restrict__ value,
                                                             const float* __restrict__ fused,
                                                             unsigned short* __restrict__ AccSw) {
    constexpr int lvl_hw[4] = {100, 50, 25, 13};
    constexpr int lvl_s[4] = {0, 10000, 12500, 13125};

    const int wg = blockIdx.x;
    const int h = wg & 7;
    const int q0 = (wg >> 3) * GQ;
    const int tid = threadIdx.x;

    __shared__ float s_ref[GQ * 8];
    __shared__ uint4 s_pd[2][GQ * 17];

    s_ref[tid] = refp[min(q0 * 8 + tid, M_TOTAL * 8 - 1)];
    __syncthreads();

#pragma unroll
    for (int jj = 0; jj < 2; ++jj) {
        const int job = jj * 256 + tid;          // 0..511
        const int qq = job >> 4;                 // 0..31
        const int t16 = job & 15;                // l*4+p
        const int l = t16 >> 2;
        const int bq = min(q0 + qq, M_TOTAL - 1);
        const int b = (bq >= LQ_C) ? 1 : 0;

        // softmax over the 16 (l,p) logits of head h (16 consecutive lanes)
        const float logit = fused[(size_t)bq * 384 + 256 + h * 16 + t16];
        float m = logit;
#pragma unroll
        for (int mask = 1; mask < 16; mask <<= 1) m = fmaxf(m, __shfl_xor(m, mask));
        const float e = expf(logit - m);
        float s = e;
#pragma unroll
        for (int mask = 1; mask < 16; mask <<= 1) s += __shfl_xor(s, mask);
        const float aw = e / s;

        const int whl = lvl_hw[l];
        const float fwh = (float)whl;
        const float2 oxy = *(const float2*)(fused + (size_t)bq * 384 + (h * 16 + t16) * 2);
        const float x = s_ref[qq * 8 + l * 2] * fwh + oxy.x - 0.5f;
        const float y = s_ref[qq * 8 + l * 2 + 1] * fwh + oxy.y - 0.5f;
        const float x0f = floorf(x), y0f = floorf(y);
        const float tx = x - x0f, ty = y - y0f;
        const int ix0 = (int)x0f, iy0 = (int)y0f;

        const bool xv0 = (unsigned)ix0 < (unsigned)whl;
        const bool xv1 = (unsigned)(ix0 + 1) < (unsigned)whl;
        const bool yv0 = (unsigned)iy0 < (unsigned)whl;
        const bool yv1 = (unsigned)(iy0 + 1) < (unsigned)whl;

        // pair base x: clamp to [-1, w-1]; invalid halves carry zero weight
        const int cxp = min(max(ix0, -1), whl - 1);
        const int cy0 = min(max(iy0, 0), whl - 1);
        const int cy1 = min(max(iy0 + 1, 0), whl - 1);

        const int posb = (b * 8 + h) * LEN_IN_C + lvl_s[l];
        const int offT = (posb + cy0 * whl + cxp) * 64;   // BYTE offsets, 128-B pairs
        const int offB = (posb + cy1 * whl + cxp) * 64;
        const float w00 = (xv0 && yv0) ? aw * (1.f - tx) * (1.f - ty) : 0.f;
        const float w01 = (xv1 && yv0) ? aw * tx * (1.f - ty) : 0.f;
        const float w10 = (xv0 && yv1) ? aw * (1.f - tx) * ty : 0.f;
        const float w11 = (xv1 && yv1) ? aw * tx * ty : 0.f;
        const int slot = qq * 17 + t16;
        uint4 d0, d1;
        d0.x = (unsigned)offT; d0.y = (unsigned)offB;
        d0.z = __float_as_uint(w00); d0.w = __float_as_uint(w10);   // left corner
        d1.x = (unsigned)offT; d1.y = (unsigned)offB;
        d1.z = __float_as_uint(w01); d1.w = __float_as_uint(w11);   // right corner
        s_pd[0][slot] = d0;
        s_pd[1][slot] = d1;
    }
    __syncthreads();

    const int qq = tid >> 3;
    const int l8 = tid & 7;
    const char* vbp = (const char*)value + l8 * 16;
    const int side = (l8 >> 2) & 1;
    const uint4* pd = &s_pd[side][qq * 17];

    uint4 dsc[2][4];
    uint4 vt[2][4], vb[2][4];
#pragma unroll
    for (int j = 0; j < 4; ++j) dsc[0][j] = pd[j];
#pragma unroll
    for (int j = 0; j < 4; ++j) {
        vt[0][j] = *(const uint4*)(vbp + (int)dsc[0][j].x);
        vb[0][j] = *(const uint4*)(vbp + (int)dsc[0][j].y);
    }

    float a0 = 0.f, a1 = 0.f, a2 = 0.f, a3 = 0.f;
    float a4 = 0.f, a5 = 0.f, a6 = 0.f, a7 = 0.f;
#pragma unroll
    for (int c = 0; c < 4; ++c) {
        const int cur = c & 1;
        const int nxt = cur ^ 1;
        if (c < 3) {
#pragma unroll
            for (int j = 0; j < 4; ++j) dsc[nxt][j] = pd[(c + 1) * 4 + j];
#pragma unroll
            for (int j = 0; j < 4; ++j) {
                vt[nxt][j] = *(const uint4*)(vbp + (int)dsc[nxt][j].x);
                vb[nxt][j] = *(const uint4*)(vbp + (int)dsc[nxt][j].y);
            }
        }
#pragma unroll
        for (int j = 0; j < 4; ++j) {
            const float wt = __uint_as_float(dsc[cur][j].z);
            const float wb = __uint_as_float(dsc[cur][j].w);
            const uint4 t4 = vt[cur][j];
            const uint4 b4 = vb[cur][j];
            FMAMIX_LO(a0, t4.x, wt); FMAMIX_HI(a1, t4.x, wt);
            FMAMIX_LO(a2, t4.y, wt); FMAMIX_HI(a3, t4.y, wt);
            FMAMIX_LO(a4, t4.z, wt); FMAMIX_HI(a5, t4.z, wt);
            FMAMIX_LO(a6, t4.w, wt); FMAMIX_HI(a7, t4.w, wt);
            FMAMIX_LO(a0, b4.x, wb); FMAMIX_HI(a1, b4.x, wb);
            FMAMIX_LO(a2, b4.y, wb); FMAMIX_HI(a3, b4.y, wb);
            FMAMIX_LO(a4, b4.z, wb); FMAMIX_HI(a5, b4.z, wb);
            FMAMIX_LO(a6, b4.w, wb); FMAMIX_HI(a7, b4.w, wb);
        }
    }

    a0 += __shfl_xor(a0, 4); a1 += __shfl_xor(a1, 4);
    a2 += __shfl_xor(a2, 4); a3 += __shfl_xor(a3, 4);
    a4 += __shfl_xor(a4, 4); a5 += __shfl_xor(a5, 4);
    a6 += __shfl_xor(a6, 4); a7 += __shfl_xor(a7, 4);

    const int bq = q0 + qq;
    if (side == 0 && bq < M_TOTAL) {
        // write swizzled A-fragment: row = bq, col = h*32 + (l8&3)*8 (+0..7)
        const int rt = bq >> 4, mm = bq & 15;
        const int unit = (rt * 8 + h) * 64 + ((l8 & 3) * 16 + mm);
        uint4 o;
        o.x = cvtpk_bf16(a0, a1);
        o.y = cvtpk_bf16(a2, a3);
        o.z = cvtpk_bf16(a4, a5);
        o.w = cvtpk_bf16(a6, a7);
        *(uint4*)(AccSw + (size_t)unit * 8) = o;
    }
}

extern "C" void kernel_launch(void* const* d_in, const int* in_sizes, int n_in,
                              void* d_out, int out_size, void* d_ws, size_t ws_size,
                              hipStream_t stream) {
    const float* query  = (const float*)d_in[0];
    const float* refp   = (const float*)d_in[1];
    const float* inflat = (const float*)d_in[2];
    const float* Wv    = (const float*)d_in[4];
    const float* bv    = (const float*)d_in[5];
    const float* Woff  = (const float*)d_in[6];
    const float* boff  = (const float*)d_in[7];
    const float* Wattn = (const float*)d_in[8];
    const float* battn = (const float*)d_in[9];
    const float* Wout  = (const float*)d_in[10];
    const float* bout  = (const float*)d_in[11];
    float* out = (float*)d_out;

    char* p = (char*)d_ws;
    unsigned short* AccSw = (unsigned short*)p;
    p += (size_t)MT_TILES * 8 * 64 * 8 * sizeof(unsigned short);          // 13.6 MB
    unsigned short* BswV = (unsigned short*)p;   p += (size_t)8 * 16 * 64 * 8 * 2;
    unsigned short* BswOA = (unsigned short*)p;  p += (size_t)8 * 24 * 64 * 8 * 2;
    unsigned short* BswO = (unsigned short*)p;   p += (size_t)8 * 16 * 64 * 8 * 2;
    float* fbias = (float*)p;                    p += 384 * sizeof(float);
    unsigned short* value = (unsigned short*)p + 32;                      // 64 B front pad
    p += ((size_t)M_TOTAL * 256 + 64) * sizeof(unsigned short);           // + 64 B back pad
    float* fused = (float*)p;                    p += (size_t)M_TOTAL * 384 * 4;

    const int M = M_TOTAL;

    conv_weights_kernel<<<115, 256, 0, stream>>>(Wv, Woff, Wattn, Wout, boff, battn,
                                                 BswV, BswOA, BswO, fbias, value, AccSw);
    front_gemm_kernel<<<FRONT_BLOCKS, 256, 0, stream>>>(inflat, query, BswV, BswOA,
                                                        bv, fbias, value, fused, M);
    msda_sample_kernel<<<QBLKS * 8, 256, 0, stream>>>(refp, value, fused, AccSw);
    back_gemm_kernel<<<BACK_BLOCKS, 256, 0, stream>>>(AccSw, BswO, bout, out, M);
}

// Round 8
// 189.203 us; speedup vs baseline: 1.3499x; 1.3499x over previous
//
#include <hip/hip_runtime.h>

#define NH 8
#define HD 32
#define NL 4
#define NP 4
#define DM 256
#define LEN_IN_C 13294
#define LQ_C 13294
#define B_C 2
#define M_TOTAL (B_C * LQ_C)           // 26588
#define MT_TILES 1662                  // ceil(26588/16)
#define RT32_TILES 831                 // ceil(26588/32)
#define GQ 32                          // queries per sampler block
#define QBLKS 831                      // ceil(26588/32)
#define LROWB 1040                     // fp32 LDS row stride: 1024 + 16 pad

typedef __attribute__((ext_vector_type(8))) short short8;
typedef __attribute__((ext_vector_type(4))) float floatx4;

__device__ __forceinline__ unsigned short f2bf(float x) {
    union { float f; unsigned int u; } a; a.f = x;
    unsigned int r = (a.u + 0x7FFFu + ((a.u >> 16) & 1u)) >> 16;
    return (unsigned short)r;
}
__device__ __forceinline__ unsigned short f2h(float x) {
    unsigned int r;
    asm("v_cvt_f16_f32 %0, %1" : "=v"(r) : "v"(x));
    return (unsigned short)r;
}
__device__ __forceinline__ unsigned int cvtpk_bf16(float lo, float hi) {
    unsigned int r;
    asm("v_cvt_pk_bf16_f32 %0, %1, %2" : "=v"(r) : "v"(lo), "v"(hi));
    return r;
}

// acc += f16(lo/hi half of v) * w   — one VALU op, f32 accumulate.
#define FMAMIX_LO(acc, v, w) \
    asm("v_fma_mix_f32 %0, %1, %2, %0 op_sel_hi:[1,0,0]" : "+v"(acc) : "v"(v), "v"(w))
#define FMAMIX_HI(acc, v, w) \
    asm("v_fma_mix_f32 %0, %1, %2, %0 op_sel:[1,0,0] op_sel_hi:[1,0,0]" : "+v"(acc) : "v"(v), "v"(w))

// 16-B async DMA: global -> LDS (dest = wave-uniform base + lane*16).
__device__ __forceinline__ void dma16(const float* g, float* l) {
    __builtin_amdgcn_global_load_lds(
        (const __attribute__((address_space(1))) unsigned int*)(g),
        (__attribute__((address_space(3))) unsigned int*)(l), 16, 0, 0);
}

// ---------------------------------------------------------------------------
// Weight conversions + bias fuse + pad/tail zeroing in ONE kernel.
// ---------------------------------------------------------------------------
__device__ __forceinline__ void conv_b_body(const float* __restrict__ W,
                                            unsigned short* __restrict__ Bsw,
                                            int Nsrc, int NTsrc, int NTtotal, int ntOff,
                                            int vblk) {
    const int u = vblk * 256 + threadIdx.x;
    const int lane = u & 63;
    const int unit = u >> 6;
    const int ntl = unit % NTsrc;
    const int kc = unit / NTsrc;
    const int n = ntl * 16 + (lane & 15);
    const int k0 = kc * 32 + (lane >> 4) * 8;
    short8 v;
#pragma unroll
    for (int j = 0; j < 8; ++j)
        v[j] = (short)f2bf(W[(size_t)(k0 + j) * Nsrc + n]);
    ((short8*)Bsw)[(size_t)(kc * NTtotal + ntOff + ntl) * 64 + lane] = v;
}

__global__ __launch_bounds__(256) void conv_weights_kernel(const float* __restrict__ Wv,
                                                           const float* __restrict__ Woff,
                                                           const float* __restrict__ Wattn,
                                                           const float* __restrict__ Wout,
                                                           const float* __restrict__ boff,
                                                           const float* __restrict__ battn,
                                                           unsigned short* __restrict__ BswV,
                                                           unsigned short* __restrict__ BswOA,
                                                           unsigned short* __restrict__ BswO,
                                                           float* __restrict__ fbias,
                                                           unsigned short* __restrict__ value,
                                                           unsigned short* __restrict__ AccSw) {
    const int blk = blockIdx.x;
    if (blk < 32)        conv_b_body(Wv,    BswV,  256, 16, 16, 0,  blk);
    else if (blk < 64)   conv_b_body(Woff,  BswOA, 256, 16, 24, 0,  blk - 32);
    else if (blk < 80)   conv_b_body(Wattn, BswOA, 128,  8, 24, 16, blk - 64);
    else if (blk < 112)  conv_b_body(Wout,  BswO,  256, 16, 16, 0,  blk - 80);
    else if (blk < 114) {
        const int t = (blk - 112) * 256 + threadIdx.x;
        if (t < 384) fbias[t] = (t < 256) ? boff[t] : battn[t - 256];
        else if (t < 416) {
            const int j = t - 384;
            value[-32 + j] = 0;                            // front pad (64 B)
            value[(size_t)M_TOTAL * 256 + j] = 0;          // back pad (64 B)
        }
    } else {
        // zero the tail rows 26588..26591 of AccSw (rt=1661, m=12..15)
        const int idx = threadIdx.x;
        if (idx < 128) {
            const int kc = idx >> 4;
            const int sub = idx & 15;
            const int lane = (12 + (sub & 3)) + 16 * (sub >> 2);
            const size_t unit = (size_t)(1661 * 8 + kc) * 64 + lane;
            short8 z = (short8){0, 0, 0, 0, 0, 0, 0, 0};
            ((short8*)AccSw)[unit] = z;
        }
    }
}

// ---------------------------------------------------------------------------
// Front GEMM: DMA-staged fp32 A tile (32 x 256, row stride 1040 B so the
// ds_read_b128 bank-group map (m+2q)%8 is even), bf16 pack at fragment-read
// time. 1662 even/odd blocks (R3/R4-proven structure).
// OUTMODE 0: fp32 row-major [M, NT*16].  OUTMODE 1: FP16 head-major value
//   layout value[((b*8+h)*LEN + pos)*32 + d].
// ---------------------------------------------------------------------------
template <int NT, int OUTMODE>
__device__ __forceinline__ void tile_compute_f32lds(const float* __restrict__ sA,
                                                    const unsigned short* __restrict__ Bsw,
                                                    const float* __restrict__ bias,
                                                    void* __restrict__ Cout, int M, int trow,
                                                    int lane, int wave) {
    constexpr int NTW = NT / 4;
    const int m = lane & 15;
    const int q = lane >> 4;
    const short8* Bu = (const short8*)Bsw;

    floatx4 acc[2][NTW];
#pragma unroll
    for (int r = 0; r < 2; ++r)
#pragma unroll
        for (int t = 0; t < NTW; ++t) acc[r][t] = (floatx4){0.f, 0.f, 0.f, 0.f};

#pragma unroll 2
    for (int kc = 0; kc < 8; ++kc) {
        short8 a[2];
#pragma unroll
        for (int r = 0; r < 2; ++r) {
            const char* fb = (const char*)sA + (m + r * 16) * LROWB + kc * 128 + q * 32;
            const float4 f0 = *(const float4*)fb;
            const float4 f1 = *(const float4*)(fb + 16);
            union { uint4 u; short8 s; } c;
            c.u.x = cvtpk_bf16(f0.x, f0.y); c.u.y = cvtpk_bf16(f0.z, f0.w);
            c.u.z = cvtpk_bf16(f1.x, f1.y); c.u.w = cvtpk_bf16(f1.z, f1.w);
            a[r] = c.s;
        }
#pragma unroll
        for (int t = 0; t < NTW; ++t) {
            const short8 b = Bu[(size_t)(kc * NT + wave * NTW + t) * 64 + lane];
            acc[0][t] = __builtin_amdgcn_mfma_f32_16x16x32_bf16(a[0], b, acc[0][t], 0, 0, 0);
            acc[1][t] = __builtin_amdgcn_mfma_f32_16x16x32_bf16(a[1], b, acc[1][t], 0, 0, 0);
        }
    }

    const int N = NT * 16;
    const int colq = lane & 15;
    const int rowq = (lane >> 4) * 4;
#pragma unroll
    for (int t = 0; t < NTW; ++t) {
        const int col = (wave * NTW + t) * 16 + colq;
        const float bc = bias[col];
#pragma unroll
        for (int r = 0; r < 2; ++r) {
#pragma unroll
            for (int reg = 0; reg < 4; ++reg) {
                const int row = trow + r * 16 + rowq + reg;
                if (row < M) {
                    const float v = acc[r][t][reg] + bc;
                    if (OUTMODE == 1) {
                        const int bb = row >= LEN_IN_C;
                        const int pos = row - (bb ? LEN_IN_C : 0);
                        const int hh = col >> 5;
                        const int dd = col & 31;
                        ((unsigned short*)Cout)[((size_t)((bb << 3) + hh) * LEN_IN_C + pos) * 32 + dd] = f2h(v);
                    } else {
                        ((float*)Cout)[(size_t)row * N + col] = v;
                    }
                }
            }
        }
    }
}

__global__ __launch_bounds__(256) void front_gemm_kernel(const float* __restrict__ inflat,
                                                         const float* __restrict__ query,
                                                         const unsigned short* __restrict__ BswV,
                                                         const unsigned short* __restrict__ BswOA,
                                                         const float* __restrict__ bv,
                                                         const float* __restrict__ fbias,
                                                         unsigned short* __restrict__ value,
                                                         float* __restrict__ fused, int M) {
    __shared__ float sA[32 * LROWB / 4];          // 33280 B
    const int tid = threadIdx.x;
    const int lane = tid & 63;
    const int wave = tid >> 6;
    const int x = blockIdx.x;
    const int flavor = x & 1;                     // 0: value GEMM, 1: off/attn GEMM
    const int trow = (x >> 1) * 32;
    const float* A = flavor ? query : inflat;

    // stage: each wave DMAs 8 rows (wave-uniform LDS base, per-lane source)
#pragma unroll
    for (int i = 0; i < 8; ++i) {
        const int lrow = i * 4 + wave;
        const int srow = min(trow + lrow, M - 1);
        dma16(A + (size_t)srow * 256 + lane * 4,
              (float*)((char*)sA + lrow * LROWB));
    }
    __syncthreads();                              // drains vmcnt -> tile ready

    if (flavor == 0)
        tile_compute_f32lds<16, 1>(sA, BswV, bv, (void*)value, M, trow, lane, wave);
    else
        tile_compute_f32lds<24, 0>(sA, BswOA, fbias, (void*)fused, M, trow, lane, wave);
}

// ---------------------------------------------------------------------------
// Back GEMM (R4-proven): pre-swizzled bf16 A, two 16-row tiles per block,
// 831 blocks, plain unroll-2 kc loop.
// ---------------------------------------------------------------------------
__global__ __launch_bounds__(256) void back_gemm_kernel(const unsigned short* __restrict__ Asw,
                                                        const unsigned short* __restrict__ Bsw,
                                                        const float* __restrict__ bias,
                                                        float* __restrict__ Cout, int M) {
    constexpr int NT = 16;
    constexpr int NTW = 4;
    const int tid = threadIdx.x;
    const int lane = tid & 63;
    const int wave = tid >> 6;
    const int rt0 = blockIdx.x * 2;

    const short8* Au = (const short8*)Asw;
    const short8* Bu = (const short8*)Bsw;

    floatx4 acc[2][NTW];
#pragma unroll
    for (int r = 0; r < 2; ++r)
#pragma unroll
        for (int t = 0; t < NTW; ++t) acc[r][t] = (floatx4){0.f, 0.f, 0.f, 0.f};

#pragma unroll 2
    for (int kc = 0; kc < 8; ++kc) {
        const short8 a0 = Au[(size_t)(rt0 * 8 + kc) * 64 + lane];
        const short8 a1 = Au[(size_t)((rt0 + 1) * 8 + kc) * 64 + lane];
#pragma unroll
        for (int t = 0; t < NTW; ++t) {
            const short8 b = Bu[(size_t)(kc * NT + wave * NTW + t) * 64 + lane];
            acc[0][t] = __builtin_amdgcn_mfma_f32_16x16x32_bf16(a0, b, acc[0][t], 0, 0, 0);
            acc[1][t] = __builtin_amdgcn_mfma_f32_16x16x32_bf16(a1, b, acc[1][t], 0, 0, 0);
        }
    }

    const int colq = lane & 15;
    const int rowq = (lane >> 4) * 4;
#pragma unroll
    for (int t = 0; t < NTW; ++t) {
        const int col = (wave * NTW + t) * 16 + colq;
        const float bc = bias[col];
#pragma unroll
        for (int r = 0; r < 2; ++r) {
#pragma unroll
            for (int reg = 0; reg < 4; ++reg) {
                const int row = (rt0 + r) * 16 + rowq + reg;
                if (row < M)
                    Cout[(size_t)row * 256 + col] = acc[r][t][reg] + bc;
            }
        }
    }
}

// ---------------------------------------------------------------------------
// Sampler v8 (best-measured, unchanged): head-per-XCD + FP16 value +
// v_fma_mix_f32, 4-point chunked double-buffered gather pipeline.
// ---------------------------------------------------------------------------
__global__ __launch_bounds__(256, 4) void msda_sample_kernel(const float* __restrict__ refp,
                                                             const unsigned short* __restrict__ value,
                                                             const float* __restrict__ fused,
                                                             unsigned short* __restrict__ AccSw) {
    constexpr int lvl_hw[4] = {100, 50, 25, 13};
    constexpr int lvl_s[4] = {0, 10000, 12500, 13125};

    const int wg = blockIdx.x;
    const int h = wg & 7;
    const int q0 = (wg >> 3) * GQ;
    const int tid = threadIdx.x;

    __shared__ float s_ref[GQ * 8];
    __shared__ uint4 s_pd[2][GQ * 17];

    s_ref[tid] = refp[min(q0 * 8 + tid, M_TOTAL * 8 - 1)];
    __syncthreads();

#pragma unroll
    for (int jj = 0; jj < 2; ++jj) {
        const int job = jj * 256 + tid;          // 0..511
        const int qq = job >> 4;                 // 0..31
        const int t16 = job & 15;                // l*4+p
        const int l = t16 >> 2;
        const int bq = min(q0 + qq, M_TOTAL - 1);
        const int b = (bq >= LQ_C) ? 1 : 0;

        // softmax over the 16 (l,p) logits of head h (16 consecutive lanes)
        const float logit = fused[(size_t)bq * 384 + 256 + h * 16 + t16];
        float m = logit;
#pragma unroll
        for (int mask = 1; mask < 16; mask <<= 1) m = fmaxf(m, __shfl_xor(m, mask));
        const float e = expf(logit - m);
        float s = e;
#pragma unroll
        for (int mask = 1; mask < 16; mask <<= 1) s += __shfl_xor(s, mask);
        const float aw = e / s;

        const int whl = lvl_hw[l];
        const float fwh = (float)whl;
        const float2 oxy = *(const float2*)(fused + (size_t)bq * 384 + (h * 16 + t16) * 2);
        const float x = s_ref[qq * 8 + l * 2] * fwh + oxy.x - 0.5f;
        const float y = s_ref[qq * 8 + l * 2 + 1] * fwh + oxy.y - 0.5f;
        const float x0f = floorf(x), y0f = floorf(y);
        const float tx = x - x0f, ty = y - y0f;
        const int ix0 = (int)x0f, iy0 = (int)y0f;

        const bool xv0 = (unsigned)ix0 < (unsigned)whl;
        const bool xv1 = (unsigned)(ix0 + 1) < (unsigned)whl;
        const bool yv0 = (unsigned)iy0 < (unsigned)whl;
        const bool yv1 = (unsigned)(iy0 + 1) < (unsigned)whl;

        // pair base x: clamp to [-1, w-1]; invalid halves carry zero weight
        const int cxp = min(max(ix0, -1), whl - 1);
        const int cy0 = min(max(iy0, 0), whl - 1);
        const int cy1 = min(max(iy0 + 1, 0), whl - 1);

        const int posb = (b * 8 + h) * LEN_IN_C + lvl_s[l];
        const int offT = (posb + cy0 * whl + cxp) * 64;   // BYTE offsets, 128-B pairs
        const int offB = (posb + cy1 * whl + cxp) * 64;
        const float w00 = (xv0 && yv0) ? aw * (1.f - tx) * (1.f - ty) : 0.f;
        const float w01 = (xv1 && yv0) ? aw * tx * (1.f - ty) : 0.f;
        const float w10 = (xv0 && yv1) ? aw * (1.f - tx) * ty : 0.f;
        const float w11 = (xv1 && yv1) ? aw * tx * ty : 0.f;
        const int slot = qq * 17 + t16;
        uint4 d0, d1;
        d0.x = (unsigned)offT; d0.y = (unsigned)offB;
        d0.z = __float_as_uint(w00); d0.w = __float_as_uint(w10);   // left corner
        d1.x = (unsigned)offT; d1.y = (unsigned)offB;
        d1.z = __float_as_uint(w01); d1.w = __float_as_uint(w11);   // right corner
        s_pd[0][slot] = d0;
        s_pd[1][slot] = d1;
    }
    __syncthreads();

    const int qq = tid >> 3;
    const int l8 = tid & 7;
    const char* vbp = (const char*)value + l8 * 16;
    const int side = (l8 >> 2) & 1;
    const uint4* pd = &s_pd[side][qq * 17];

    uint4 dsc[2][4];
    uint4 vt[2][4], vb[2][4];
#pragma unroll
    for (int j = 0; j < 4; ++j) dsc[0][j] = pd[j];
#pragma unroll
    for (int j = 0; j < 4; ++j) {
        vt[0][j] = *(const uint4*)(vbp + (int)dsc[0][j].x);
        vb[0][j] = *(const uint4*)(vbp + (int)dsc[0][j].y);
    }

    float a0 = 0.f, a1 = 0.f, a2 = 0.f, a3 = 0.f;
    float a4 = 0.f, a5 = 0.f, a6 = 0.f, a7 = 0.f;
#pragma unroll
    for (int c = 0; c < 4; ++c) {
        const int cur = c & 1;
        const int nxt = cur ^ 1;
        if (c < 3) {
#pragma unroll
            for (int j = 0; j < 4; ++j) dsc[nxt][j] = pd[(c + 1) * 4 + j];
#pragma unroll
            for (int j = 0; j < 4; ++j) {
                vt[nxt][j] = *(const uint4*)(vbp + (int)dsc[nxt][j].x);
                vb[nxt][j] = *(const uint4*)(vbp + (int)dsc[nxt][j].y);
            }
        }
#pragma unroll
        for (int j = 0; j < 4; ++j) {
            const float wt = __uint_as_float(dsc[cur][j].z);
            const float wb = __uint_as_float(dsc[cur][j].w);
            const uint4 t4 = vt[cur][j];
            const uint4 b4 = vb[cur][j];
            FMAMIX_LO(a0, t4.x, wt); FMAMIX_HI(a1, t4.x, wt);
            FMAMIX_LO(a2, t4.y, wt); FMAMIX_HI(a3, t4.y, wt);
            FMAMIX_LO(a4, t4.z, wt); FMAMIX_HI(a5, t4.z, wt);
            FMAMIX_LO(a6, t4.w, wt); FMAMIX_HI(a7, t4.w, wt);
            FMAMIX_LO(a0, b4.x, wb); FMAMIX_HI(a1, b4.x, wb);
            FMAMIX_LO(a2, b4.y, wb); FMAMIX_HI(a3, b4.y, wb);
            FMAMIX_LO(a4, b4.z, wb); FMAMIX_HI(a5, b4.z, wb);
            FMAMIX_LO(a6, b4.w, wb); FMAMIX_HI(a7, b4.w, wb);
        }
    }

    a0 += __shfl_xor(a0, 4); a1 += __shfl_xor(a1, 4);
    a2 += __shfl_xor(a2, 4); a3 += __shfl_xor(a3, 4);
    a4 += __shfl_xor(a4, 4); a5 += __shfl_xor(a5, 4);
    a6 += __shfl_xor(a6, 4); a7 += __shfl_xor(a7, 4);

    const int bq = q0 + qq;
    if (side == 0 && bq < M_TOTAL) {
        // write swizzled A-fragment: row = bq, col = h*32 + (l8&3)*8 (+0..7)
        const int rt = bq >> 4, mm = bq & 15;
        const int unit = (rt * 8 + h) * 64 + ((l8 & 3) * 16 + mm);
        uint4 o;
        o.x = cvtpk_bf16(a0, a1);
        o.y = cvtpk_bf16(a2, a3);
        o.z = cvtpk_bf16(a4, a5);
        o.w = cvtpk_bf16(a6, a7);
        *(uint4*)(AccSw + (size_t)unit * 8) = o;
    }
}

extern "C" void kernel_launch(void* const* d_in, const int* in_sizes, int n_in,
                              void* d_out, int out_size, void* d_ws, size_t ws_size,
                              hipStream_t stream) {
    const float* query  = (const float*)d_in[0];
    const float* refp   = (const float*)d_in[1];
    const float* inflat = (const float*)d_in[2];
    const float* Wv    = (const float*)d_in[4];
    const float* bv    = (const float*)d_in[5];
    const float* Woff  = (const float*)d_in[6];
    const float* boff  = (const float*)d_in[7];
    const float* Wattn = (const float*)d_in[8];
    const float* battn = (const float*)d_in[9];
    const float* Wout  = (const float*)d_in[10];
    const float* bout  = (const float*)d_in[11];
    float* out = (float*)d_out;

    char* p = (char*)d_ws;
    unsigned short* AccSw = (unsigned short*)p;
    p += (size_t)MT_TILES * 8 * 64 * 8 * sizeof(unsigned short);          // 13.6 MB
    unsigned short* BswV = (unsigned short*)p;   p += (size_t)8 * 16 * 64 * 8 * 2;
    unsigned short* BswOA = (unsigned short*)p;  p += (size_t)8 * 24 * 64 * 8 * 2;
    unsigned short* BswO = (unsigned short*)p;   p += (size_t)8 * 16 * 64 * 8 * 2;
    float* fbias = (float*)p;                    p += 384 * sizeof(float);
    unsigned short* value = (unsigned short*)p + 32;                      // 64 B front pad
    p += ((size_t)M_TOTAL * 256 + 64) * sizeof(unsigned short);           // + 64 B back pad
    float* fused = (float*)p;                    p += (size_t)M_TOTAL * 384 * 4;

    const int M = M_TOTAL;

    conv_weights_kernel<<<115, 256, 0, stream>>>(Wv, Woff, Wattn, Wout, boff, battn,
                                                 BswV, BswOA, BswO, fbias, value, AccSw);
    front_gemm_kernel<<<RT32_TILES * 2, 256, 0, stream>>>(inflat, query, BswV, BswOA,
                                                          bv, fbias, value, fused, M);
    msda_sample_kernel<<<QBLKS * 8, 256, 0, stream>>>(refp, value, fused, AccSw);
    back_gemm_kernel<<<RT32_TILES, 256, 0, stream>>>(AccSw, BswO, bout, out, M);
}